// Round 2
// baseline (231.341 us; speedup 1.0000x reference)
//
#include <hip/hip_runtime.h>

#define D_DIM 640
#define M_DIM 1024
#define B_DIM 32
#define OUT_ROW 205120  // 640*641/2

typedef __bf16 bf16x8 __attribute__((ext_vector_type(8)));
typedef float f32x4 __attribute__((ext_vector_type(4)));

__device__ __forceinline__ unsigned short f2bf(float f) {
    union { float f; unsigned int u; } c; c.f = f;
    unsigned int u = c.u;
    unsigned int r = (u + 0x7fffu + ((u >> 16) & 1u)) >> 16;
    return (unsigned short)r;
}

__device__ __forceinline__ float bf2f(unsigned short h) {
    union { unsigned int u; float f; } c; c.u = ((unsigned int)h) << 16;
    return c.f;
}

__device__ __forceinline__ float block_reduce_256(float s) {
    #pragma unroll
    for (int off = 32; off > 0; off >>= 1) s += __shfl_down(s, off, 64);
    __shared__ float red[4];
    if ((threadIdx.x & 63) == 0) red[threadIdx.x >> 6] = s;
    __syncthreads();
    return red[0] + red[1] + red[2] + red[3];
}

__device__ __forceinline__ float block_reduce_512(float s) {
    #pragma unroll
    for (int off = 32; off > 0; off >>= 1) s += __shfl_down(s, off, 64);
    __shared__ float red[8];
    if ((threadIdx.x & 63) == 0) red[threadIdx.x >> 6] = s;
    __syncthreads();
    float t = 0.f;
    #pragma unroll
    for (int i = 0; i < 8; i++) t += red[i];
    return t;
}

// Kernel 1: fp32 -> bf16 cast + per-row sum of squares; zeroes accumulators.
__global__ void cast_diag_kernel(const float* __restrict__ x,
                                 unsigned short* __restrict__ xb,
                                 float* __restrict__ diag,
                                 float* __restrict__ rowsum,
                                 float* __restrict__ tot) {
    const size_t row = blockIdx.x;
    const int t = threadIdx.x;
    const float4 v = ((const float4*)(x + row * M_DIM))[t];
    float s = v.x * v.x + v.y * v.y + v.z * v.z + v.w * v.w;
    ushort4 o;
    o.x = f2bf(v.x); o.y = f2bf(v.y); o.z = f2bf(v.z); o.w = f2bf(v.w);
    ((ushort4*)(xb + row * M_DIM))[t] = o;
    float ssum = block_reduce_256(s);
    if (t == 0) { diag[row] = ssum; rowsum[row] = 0.f; }
    if (t == 1 && row < B_DIM) tot[row] = 0.f;
}

// Kernel 2: symmetric batched G = X X^T, upper-tri tiles (it<=jt), fused
// dcov epilogue (bf16 store) + rowsum/tot atomics.
// CHANGE vs prev: NO LDS STAGING, NO K-LOOP BARRIERS. Per-batch panels are
// 1.25 MB (L2/L3-resident: FETCH_SIZE showed xb read once from HBM), so LDS
// staging was pure synchronization overhead: per-iter vmcnt+s_barrier
// convoyed all 8 waves (~3400 cyc/iter vs ~500 of real work) — which is why
// doubling in-block waves in r1 didn't move the total. Now each wave loads
// its MFMA fragments global->VGPR directly (coalesced 16-row x 64 B
// segments), double-buffered in two NAMED register sets (static indexing),
// compiler-counted vmcnt, fully independent waves (attn-style TLP).
__global__ __launch_bounds__(512, 4)
void gemm_dcov_kernel(const unsigned short* __restrict__ xb,
                      const float* __restrict__ diag,
                      unsigned short* __restrict__ dcov,
                      float* __restrict__ rowsum,
                      float* __restrict__ tot) {
    const int id = blockIdx.x;
    const int bt = (id & 7) * 4 + ((id >> 3) & 3);  // batch; tiles of a batch share an XCD
    int p = id >> 5;                                 // 0..14 tile-pair index
    int it = 0, off = p;
    while (off >= 5 - it) { off -= 5 - it; ++it; }
    const int jt = it + off;
    const bool diagTile = (it == jt);

    const int tid = threadIdx.x;
    const int w = tid >> 6, l = tid & 63;
    const int wy = w >> 2, wx = w & 3;               // 2 row-bands x 4 col-bands
    const int lm = l & 15, quad = l >> 4;

    // per-lane fragment base pointers (row-major xb, stride M_DIM shorts)
    // af[mi]: rows wy*64 + mi*16 + lm ; k-slice: quad*8 + k*32 shorts
    const unsigned short* a0 = xb + ((size_t)bt * D_DIM + it * 128 + wy * 64 + lm) * M_DIM + quad * 8;
    const unsigned short* b0 = xb + ((size_t)bt * D_DIM + jt * 128 + wx * 32 + lm) * M_DIM + quad * 8;

    f32x4 acc[4][2];
    const f32x4 zero = {0.f, 0.f, 0.f, 0.f};
    #pragma unroll
    for (int i = 0; i < 4; i++)
        #pragma unroll
        for (int j = 0; j < 2; j++) acc[i][j] = zero;

    bf16x8 aA[4], bA[2], aB[4], bB[2];

    auto LD = [&](bf16x8* a, bf16x8* b, int k) {
        const unsigned short* pa = a0 + k * 32;
        const unsigned short* pb = b0 + k * 32;
        #pragma unroll
        for (int mi = 0; mi < 4; mi++)
            a[mi] = *(const bf16x8*)(pa + (size_t)mi * 16 * M_DIM);
        #pragma unroll
        for (int ni = 0; ni < 2; ni++)
            b[ni] = *(const bf16x8*)(pb + (size_t)ni * 16 * M_DIM);
    };
    auto MM = [&](bf16x8* a, bf16x8* b) {
        __builtin_amdgcn_s_setprio(1);
        #pragma unroll
        for (int mi = 0; mi < 4; mi++)
            #pragma unroll
            for (int ni = 0; ni < 2; ni++)
                acc[mi][ni] = __builtin_amdgcn_mfma_f32_16x16x32_bf16(
                    a[mi], b[ni], acc[mi][ni], 0, 0, 0);
        __builtin_amdgcn_s_setprio(0);
    };

    LD(aA, bA, 0);
    for (int k = 0; k < 32; k += 2) {
        LD(aB, bB, k + 1);          // issue next-slice loads before consuming
        MM(aA, bA);
        if (k + 2 < 32) LD(aA, bA, k + 2);
        MM(aB, bB);
    }

    // stage diag slices in (small) LDS
    __shared__ float sd[256];
    if (tid < 128)      sd[tid] = diag[(size_t)bt * D_DIM + it * 128 + tid];
    else if (tid < 256) sd[tid] = diag[(size_t)bt * D_DIM + jt * 128 + (tid - 128)];
    __syncthreads();

    const float temp = 7.62939453125e-07f;  // 1/(2*640*1024)
    unsigned short* dbase = dcov + (size_t)bt * D_DIM * D_DIM;
    float* rs = rowsum + (size_t)bt * D_DIM;
    float ts = 0.f;
    float cp[2] = {0.f, 0.f};

    #pragma unroll
    for (int mi = 0; mi < 4; mi++) {
        #pragma unroll
        for (int r = 0; r < 4; r++) {
            const int lrow = wy * 64 + mi * 16 + quad * 4 + r;
            const int grow = it * 128 + lrow;
            const float di = sd[lrow];
            float rp = 0.f;
            #pragma unroll
            for (int ni = 0; ni < 2; ni++) {
                const int lcol = wx * 32 + ni * 16 + lm;
                const int gcol = jt * 128 + lcol;
                const float dj = sd[128 + lcol];
                const float g = acc[mi][ni][r];
                const float v = sqrtf(fmaf(temp, fmaxf(di + dj - 2.f * g, 0.f), 1e-5f));
                dbase[(size_t)grow * D_DIM + gcol] = f2bf(v);
                rp += v;
                cp[ni] += v;
            }
            ts += rp;
            rp += __shfl_down(rp, 8, 16);
            rp += __shfl_down(rp, 4, 16);
            rp += __shfl_down(rp, 2, 16);
            rp += __shfl_down(rp, 1, 16);
            if (lm == 0) atomicAdd(&rs[grow], rp);
        }
    }
    if (!diagTile) {
        // mirrored lower tile (jt,it): its row sums == our column sums
        #pragma unroll
        for (int ni = 0; ni < 2; ni++) {
            float c = cp[ni];
            c += __shfl_down(c, 32);
            c += __shfl_down(c, 16);
            if (l < 16) atomicAdd(&rs[jt * 128 + wx * 32 + ni * 16 + lm], c);
        }
    }
    float bs = block_reduce_512(ts);
    if (tid == 0) atomicAdd(&tot[bt], diagTile ? bs : 2.f * bs);
}

// Kernel 3: double centering + triu gather (bf16 dcov read, fp32 out).
__global__ void output_kernel(const unsigned short* __restrict__ dcov,
                              const float* __restrict__ rowsum,
                              const float* __restrict__ tot,
                              float* __restrict__ out) {
    const int b = blockIdx.x / D_DIM;
    const int i = blockIdx.x - b * D_DIM;
    const float inv_d = 1.f / (float)D_DIM;
    const float rmi = rowsum[(size_t)b * D_DIM + i] * inv_d;
    const float tm = tot[b] * (inv_d * inv_d);
    const unsigned short* drow = dcov + ((size_t)b * D_DIM + i) * D_DIM;
    const float* rs = rowsum + (size_t)b * D_DIM;
    float* orow = out + (size_t)b * OUT_ROW + (size_t)i * D_DIM - (size_t)i * (i - 1) / 2;
    for (int j = i + threadIdx.x; j < D_DIM; j += 256)
        orow[j - i] = bf2f(drow[j]) - rmi - rs[j] * inv_d + tm;
}

extern "C" void kernel_launch(void* const* d_in, const int* in_sizes, int n_in,
                              void* d_out, int out_size, void* d_ws, size_t ws_size,
                              hipStream_t stream) {
    const float* x = (const float*)d_in[0];
    float* out = (float*)d_out;

    char* ws = (char*)d_ws;
    unsigned short* xb = (unsigned short*)ws;                 // 41,943,040 B
    size_t off = 41943040;
    float* diag = (float*)(ws + off);           off += 81920;
    unsigned short* dcov = (unsigned short*)(ws + off); off += 26214400;  // bf16
    float* rowsum = (float*)(ws + off);         off += 81920;
    float* tot = (float*)(ws + off);            off += 256;

    cast_diag_kernel<<<dim3(B_DIM * D_DIM), 256, 0, stream>>>(x, xb, diag, rowsum, tot);
    gemm_dcov_kernel<<<dim3(480), 512, 0, stream>>>(xb, diag, dcov, rowsum, tot);
    output_kernel<<<dim3(B_DIM * D_DIM), 256, 0, stream>>>(dcov, rowsum, tot, out);
}

// Round 4
// 185.573 us; speedup vs baseline: 1.2466x; 1.2466x over previous
//
#include <hip/hip_runtime.h>

#define D_DIM 640
#define M_DIM 1024
#define B_DIM 32
#define OUT_ROW 205120  // 640*641/2

typedef __bf16 bf16x8 __attribute__((ext_vector_type(8)));
typedef float f32x4 __attribute__((ext_vector_type(4)));

__device__ __forceinline__ unsigned short f2bf(float f) {
    union { float f; unsigned int u; } c; c.f = f;
    unsigned int u = c.u;
    unsigned int r = (u + 0x7fffu + ((u >> 16) & 1u)) >> 16;
    return (unsigned short)r;
}

__device__ __forceinline__ float bf2f(unsigned short h) {
    union { unsigned int u; float f; } c; c.u = ((unsigned int)h) << 16;
    return c.f;
}

__device__ __forceinline__ void gload_lds16(const unsigned short* g, unsigned short* l) {
    __builtin_amdgcn_global_load_lds(
        (const __attribute__((address_space(1))) unsigned int*)g,
        (__attribute__((address_space(3))) unsigned int*)l,
        16, 0, 0);
}

__device__ __forceinline__ float block_reduce_256(float s) {
    #pragma unroll
    for (int off = 32; off > 0; off >>= 1) s += __shfl_down(s, off, 64);
    __shared__ float red[4];
    if ((threadIdx.x & 63) == 0) red[threadIdx.x >> 6] = s;
    __syncthreads();
    return red[0] + red[1] + red[2] + red[3];
}

// Kernel 1: fp32 -> bf16 cast + per-row sum of squares; zeroes accumulators.
__global__ void cast_diag_kernel(const float* __restrict__ x,
                                 unsigned short* __restrict__ xb,
                                 float* __restrict__ diag,
                                 float* __restrict__ rowsum,
                                 float* __restrict__ tot) {
    const size_t row = blockIdx.x;
    const int t = threadIdx.x;
    const float4 v = ((const float4*)(x + row * M_DIM))[t];
    float s = v.x * v.x + v.y * v.y + v.z * v.z + v.w * v.w;
    ushort4 o;
    o.x = f2bf(v.x); o.y = f2bf(v.y); o.z = f2bf(v.z); o.w = f2bf(v.w);
    ((ushort4*)(xb + row * M_DIM))[t] = o;
    float ssum = block_reduce_256(s);
    if (t == 0) { diag[row] = ssum; rowsum[row] = 0.f; }
    if (t == 1 && row < B_DIM) tot[row] = 0.f;
}

// Kernel 2: symmetric batched G = X X^T, upper-tri 128-blocks split into
// 128x64 tiles (it<=jt, jh in {0,1}), fused dcov epilogue + rowsum/tot.
// r3 POST-MORTEM: the 3-phase/one-barrier pipeline RACED (nondeterministic
// post-timing divergence, 6.8e-3) — confirming the r0 session note that
// 3 phases need a second read-protect barrier. This round: r3's grid
// (960 blocks x 256 thr, 128x64 tiles — functionally verified, first check
// passed) merged into the PROVEN r0/r1 pipeline skeleton: 4 phases x 12 KB
// = 48 KB, depth-3 prologue, one barrier/iter, vmcnt ladder 6/3/0
// (3 loads/issue), no setprio. 48 KB -> 3 blocks/CU = 12 waves/CU in 3
// independent barrier domains (vs r1's 2 domains) to attack the measured
// latency-bound convoy (gemm ~34 us graph-mode, floor ~12-15).
// Safety: issue(k+3) overwrites phase (k+3)&3 = (k-1)&3, whose reads
// completed before the top-of-iter barrier (identical protection distance
// to r0/r1, proven twice on hardware).
__global__ __launch_bounds__(256, 3)
void gemm_dcov_kernel(const unsigned short* __restrict__ xb,
                      const float* __restrict__ diag,
                      unsigned short* __restrict__ dcov,
                      float* __restrict__ rowsum,
                      float* __restrict__ tot) {
    // 4 phases x (A 128x32 = 4096 shorts + B 64x32 = 2048 shorts) = 48 KB
    __shared__ __align__(16) unsigned short smem[24576];

    const int id = blockIdx.x;
    const int bt = (id & 7) * 4 + ((id >> 3) & 3);  // batch; same-batch tiles share an XCD
    const int rest = id >> 5;                        // 0..29
    const int jh = rest & 1;                         // column half of the 128-block
    int p2 = rest >> 1;                              // 0..14 tile-pair index
    int it = 0, off = p2;
    while (off >= 5 - it) { off -= 5 - it; ++it; }
    const int jt = it + off;
    const bool diagTile = (it == jt);

    const int tid = threadIdx.x;
    const int w = tid >> 6, l = tid & 63;
    const int wy = w >> 1, wx = w & 1;               // 2 row-bands x 2 col-bands
    const int lm = l & 15, quad = l >> 4;

    const unsigned short* gA = xb + ((size_t)bt * D_DIM + it * 128) * M_DIM;
    const unsigned short* gB = xb + ((size_t)bt * D_DIM + jt * 128 + jh * 64) * M_DIM;

    // staging: lane writes LDS at tid*16B (fixed by global_load_lds); pick the
    // global source chunk so LDS gets XOR-swizzled (bank-conflict-free reads).
    // Invariant: LDS[row][slot c] holds global chunk c ^ ((row>>1)&3).
    const int r0 = tid >> 2;                         // 0..63
    const int cl = (((tid & 3) ^ ((tid >> 3) & 3)) << 3);
    const size_t aoff = (size_t)r0 * M_DIM + cl;
    const int ldst = tid * 8;                        // shorts; 256*8 = 2048 = 4 KB

    auto issue = [&](int k, int ph) {
        unsigned short* sA = smem + ph * 6144;
        unsigned short* sB = sA + 4096;
        const int koff = k * 32;
        gload_lds16(gA + aoff + koff, sA + ldst);                             // A rows 0..63
        gload_lds16(gA + aoff + (size_t)64 * M_DIM + koff, sA + ldst + 2048); // A rows 64..127
        gload_lds16(gB + aoff + koff, sB + ldst);                             // B rows 0..63
    };

    f32x4 acc[4][2];
    const f32x4 zero = {0.f, 0.f, 0.f, 0.f};
    #pragma unroll
    for (int i = 0; i < 4; i++)
        #pragma unroll
        for (int j = 0; j < 2; j++) acc[i][j] = zero;

    const int sw = ((quad ^ ((lm >> 1) & 3)) << 3);  // swizzled chunk offset

    issue(0, 0); issue(1, 1); issue(2, 2);  // 9 loads in flight per lane (depth-3)

    for (int k = 0; k < 32; ++k) {
        // wait only for phase k's 3 loads; keep 6 more in flight.
        if (k < 30)       asm volatile("s_waitcnt vmcnt(6)" ::: "memory");
        else if (k == 30) asm volatile("s_waitcnt vmcnt(3)" ::: "memory");
        else              asm volatile("s_waitcnt vmcnt(0)" ::: "memory");
        asm volatile("s_barrier" ::: "memory");
        // prefetch k+3 into phase (k+3)&3 = buffer last read at iter k-1,
        // which the top-of-loop barrier already protects (proven r0/r1 form).
        if (k + 3 < 32) issue(k + 3, (k + 3) & 3);

        const unsigned short* sA = smem + (k & 3) * 6144;
        const unsigned short* sB = sA + 4096;
        bf16x8 af[4], bfr[2];
        #pragma unroll
        for (int mi = 0; mi < 4; mi++)
            af[mi] = *(const bf16x8*)&sA[(wy * 64 + mi * 16 + lm) * 32 + sw];
        #pragma unroll
        for (int ni = 0; ni < 2; ni++)
            bfr[ni] = *(const bf16x8*)&sB[(wx * 32 + ni * 16 + lm) * 32 + sw];

        #pragma unroll
        for (int mi = 0; mi < 4; mi++)
            #pragma unroll
            for (int ni = 0; ni < 2; ni++)
                acc[mi][ni] = __builtin_amdgcn_mfma_f32_16x16x32_bf16(
                    af[mi], bfr[ni], acc[mi][ni], 0, 0, 0);
    }

    // stage diag slices in LDS (phase-0 bytes; phase 0 last read at iter 28,
    // no writes in flight after iter 31's vmcnt(0); trailing waves read
    // phase 3 only — disjoint)
    float* sd = (float*)smem;
    if (tid < 128)      sd[tid] = diag[(size_t)bt * D_DIM + it * 128 + tid];
    else if (tid < 192) sd[tid] = diag[(size_t)bt * D_DIM + jt * 128 + jh * 64 + (tid - 128)];
    __syncthreads();

    const float temp = 7.62939453125e-07f;  // 1/(2*640*1024)
    unsigned short* dbase = dcov + (size_t)bt * D_DIM * D_DIM;
    float* rs = rowsum + (size_t)bt * D_DIM;
    float ts = 0.f;
    float cp[2] = {0.f, 0.f};

    #pragma unroll
    for (int mi = 0; mi < 4; mi++) {
        #pragma unroll
        for (int r = 0; r < 4; r++) {
            const int lrow = wy * 64 + mi * 16 + quad * 4 + r;
            const int grow = it * 128 + lrow;
            const float di = sd[lrow];
            float rp = 0.f;
            #pragma unroll
            for (int ni = 0; ni < 2; ni++) {
                const int lcol = wx * 32 + ni * 16 + lm;
                const int gcol = jt * 128 + jh * 64 + lcol;
                const float dj = sd[128 + lcol];
                const float g = acc[mi][ni][r];
                const float v = sqrtf(fmaf(temp, fmaxf(di + dj - 2.f * g, 0.f), 1e-5f));
                dbase[(size_t)grow * D_DIM + gcol] = f2bf(v);
                rp += v;
                cp[ni] += v;
            }
            ts += rp;
            rp += __shfl_down(rp, 8, 16);
            rp += __shfl_down(rp, 4, 16);
            rp += __shfl_down(rp, 2, 16);
            rp += __shfl_down(rp, 1, 16);
            if (lm == 0) atomicAdd(&rs[grow], rp);
        }
    }
    if (!diagTile) {
        // mirrored lower tile (jt,it): its row sums == our column sums
        #pragma unroll
        for (int ni = 0; ni < 2; ni++) {
            float c = cp[ni];
            c += __shfl_down(c, 32);
            c += __shfl_down(c, 16);
            if (l < 16) atomicAdd(&rs[jt * 128 + jh * 64 + wx * 32 + ni * 16 + lm], c);
        }
    }
    float bs = block_reduce_256(ts);
    if (tid == 0) atomicAdd(&tot[bt], diagTile ? bs : 2.f * bs);
}

// Kernel 3: double centering + triu gather (bf16 dcov read, fp32 out).
// Balanced: block q handles rows q and 639-q (lengths 640-q and q+1, sum 641).
__global__ void output_kernel(const unsigned short* __restrict__ dcov,
                              const float* __restrict__ rowsum,
                              const float* __restrict__ tot,
                              float* __restrict__ out) {
    const int b = blockIdx.x / 320;
    const int q = blockIdx.x - b * 320;
    const float inv_d = 1.f / (float)D_DIM;
    const float tm = tot[b] * (inv_d * inv_d);
    const float* rs = rowsum + (size_t)b * D_DIM;

    #pragma unroll
    for (int half = 0; half < 2; half++) {
        const int i = half ? (D_DIM - 1 - q) : q;
        const float rmi = rs[i] * inv_d;
        const unsigned short* drow = dcov + ((size_t)b * D_DIM + i) * D_DIM;
        float* orow = out + (size_t)b * OUT_ROW + (size_t)i * D_DIM - (size_t)i * (i - 1) / 2;
        for (int j = i + threadIdx.x; j < D_DIM; j += 256)
            orow[j - i] = bf2f(drow[j]) - rmi - rs[j] * inv_d + tm;
    }
}

extern "C" void kernel_launch(void* const* d_in, const int* in_sizes, int n_in,
                              void* d_out, int out_size, void* d_ws, size_t ws_size,
                              hipStream_t stream) {
    const float* x = (const float*)d_in[0];
    float* out = (float*)d_out;

    char* ws = (char*)d_ws;
    unsigned short* xb = (unsigned short*)ws;                 // 41,943,040 B
    size_t off = 41943040;
    float* diag = (float*)(ws + off);           off += 81920;
    unsigned short* dcov = (unsigned short*)(ws + off); off += 26214400;  // bf16
    float* rowsum = (float*)(ws + off);         off += 81920;
    float* tot = (float*)(ws + off);            off += 256;

    cast_diag_kernel<<<dim3(B_DIM * D_DIM), 256, 0, stream>>>(x, xb, diag, rowsum, tot);
    gemm_dcov_kernel<<<dim3(960), 256, 0, stream>>>(xb, diag, dcov, rowsum, tot);
    output_kernel<<<dim3(B_DIM * 320), 256, 0, stream>>>(dcov, rowsum, tot, out);
}

// Round 5
// 184.762 us; speedup vs baseline: 1.2521x; 1.0044x over previous
//
#include <hip/hip_runtime.h>

#define D_DIM 640
#define M_DIM 1024
#define B_DIM 32
#define OUT_ROW 205120  // 640*641/2

typedef __bf16 bf16x8 __attribute__((ext_vector_type(8)));
typedef float f32x4 __attribute__((ext_vector_type(4)));

__device__ __forceinline__ unsigned short f2bf(float f) {
    union { float f; unsigned int u; } c; c.f = f;
    unsigned int u = c.u;
    unsigned int r = (u + 0x7fffu + ((u >> 16) & 1u)) >> 16;
    return (unsigned short)r;
}

__device__ __forceinline__ float bf2f(unsigned short h) {
    union { unsigned int u; float f; } c; c.u = ((unsigned int)h) << 16;
    return c.f;
}

__device__ __forceinline__ void gload_lds16(const unsigned short* g, unsigned short* l) {
    __builtin_amdgcn_global_load_lds(
        (const __attribute__((address_space(1))) unsigned int*)g,
        (__attribute__((address_space(3))) unsigned int*)l,
        16, 0, 0);
}

__device__ __forceinline__ float block_reduce_256(float s) {
    #pragma unroll
    for (int off = 32; off > 0; off >>= 1) s += __shfl_down(s, off, 64);
    __shared__ float red[4];
    if ((threadIdx.x & 63) == 0) red[threadIdx.x >> 6] = s;
    __syncthreads();
    return red[0] + red[1] + red[2] + red[3];
}

// Kernel 1: fp32 -> bf16 cast + per-row sum of squares; zeroes accumulators.
__global__ void cast_diag_kernel(const float* __restrict__ x,
                                 unsigned short* __restrict__ xb,
                                 float* __restrict__ diag,
                                 float* __restrict__ rowsum,
                                 float* __restrict__ tot) {
    const size_t row = blockIdx.x;
    const int t = threadIdx.x;
    const float4 v = ((const float4*)(x + row * M_DIM))[t];
    float s = v.x * v.x + v.y * v.y + v.z * v.z + v.w * v.w;
    ushort4 o;
    o.x = f2bf(v.x); o.y = f2bf(v.y); o.z = f2bf(v.z); o.w = f2bf(v.w);
    ((ushort4*)(xb + row * M_DIM))[t] = o;
    float ssum = block_reduce_256(s);
    if (t == 0) { diag[row] = ssum; rowsum[row] = 0.f; }
    if (t == 1 && row < B_DIM) tot[row] = 0.f;
}

// Kernel 2: symmetric batched G = X X^T, upper-tri 64x64 tiles (it<=jt),
// fused dcov epilogue + rowsum/tot atomics.
// r0-r4 post-mortem: graph-mode gemm has been stuck at ~43-56 us (vs a
// ~12-15 us resource floor) across every shared-LDS variant because the
// per-iter vmcnt+s_barrier convoys all waves of a block; rearranging
// block/domain counts (r1: 8 waves, r4: 960 blocks) never moved it.
// THIS ROUND: single-wave blocks, wave-private LDS, ZERO barriers.
// One wave owns a 64x64 tile (acc[4][4], 16 MFMA + 8 ds_read_b128/iter),
// 2-phase x 8 KB = 16 KB/block -> 10 blocks/CU, ~7 independent
// wave-streams/CU. Ordering is per-wave counters only:
//   - vmcnt(8) gates this wave's own 8 phase-k gload_lds (per-wave counter)
//   - explicit lgkmcnt(0) after the fragment ds_reads, before the next
//     iter's issue, guarantees the opposite phase is consumed before
//     overwrite (r3-style cross-wave races structurally impossible).
__global__ __launch_bounds__(64, 2)
void gemm_dcov_kernel(const unsigned short* __restrict__ xb,
                      const float* __restrict__ diag,
                      unsigned short* __restrict__ dcov,
                      float* __restrict__ rowsum,
                      float* __restrict__ tot) {
    // 2 phases x (A 64x32 = 2048 shorts + B 64x32 = 2048 shorts) = 16 KB
    __shared__ __align__(16) unsigned short smem[8192];

    const int id = blockIdx.x;
    const int bt = (id & 7) * 4 + ((id >> 3) & 3);  // batch; same-batch tiles share an XCD
    int p = id >> 5;                                 // 0..54 tile index
    int it = 0, off = p;
    while (off >= 10 - it) { off -= 10 - it; ++it; }
    const int jt = it + off;
    const bool diagTile = (it == jt);

    const int l = threadIdx.x;                       // 0..63 (one wave)
    const int lm = l & 15, quad = l >> 4;

    const unsigned short* gA = xb + ((size_t)bt * D_DIM + it * 64) * M_DIM;
    const unsigned short* gB = xb + ((size_t)bt * D_DIM + jt * 64) * M_DIM;

    // staging: gload_lds writes LDS at (wave-uniform base + lane*16B); choose
    // the per-lane GLOBAL source chunk so LDS lands XOR-swizzled
    // (bank-conflict-free ds_read_b128). Invariant: LDS[row][slot c] holds
    // global chunk c ^ ((row>>1)&3). Lane l covers row l>>2 (within a 16-row
    // group), source chunk (l&3)^((l>>3)&3)  [(row>>1)&3 == (l>>3)&3].
    const int cl = (((l & 3) ^ ((l >> 3) & 3)) << 3);
    const size_t goff = (size_t)(l >> 2) * M_DIM + cl;
    const int ldst = l * 8;                          // shorts = lane*16 B

    auto issue = [&](int k, int ph) {
        unsigned short* sA = smem + ph * 4096;
        unsigned short* sB = sA + 2048;
        const int koff = k * 32;
        #pragma unroll
        for (int g = 0; g < 4; g++) {                // 16-row groups
            gload_lds16(gA + goff + (size_t)g * 16 * M_DIM + koff, sA + g * 512 + ldst);
            gload_lds16(gB + goff + (size_t)g * 16 * M_DIM + koff, sB + g * 512 + ldst);
        }
    };

    f32x4 acc[4][4];
    const f32x4 zero = {0.f, 0.f, 0.f, 0.f};
    #pragma unroll
    for (int i = 0; i < 4; i++)
        #pragma unroll
        for (int j = 0; j < 4; j++) acc[i][j] = zero;

    const int sw = ((quad ^ ((lm >> 1) & 3)) << 3);  // swizzled read slot

    issue(0, 0);
    for (int k = 0; k < 32; ++k) {
        // prefetch next phase first (depth-2). Target phase (k+1)&1 was
        // consumed at iter k-1 (its lgkmcnt(0) is program-order behind us).
        if (k + 1 < 32) {
            issue(k + 1, (k + 1) & 1);
            asm volatile("s_waitcnt vmcnt(8)" ::: "memory");  // phase k's 8 done
        } else {
            asm volatile("s_waitcnt vmcnt(0)" ::: "memory");
        }

        const unsigned short* sA = smem + (k & 1) * 4096;
        const unsigned short* sB = sA + 2048;
        bf16x8 af[4], bfr[4];
        #pragma unroll
        for (int mi = 0; mi < 4; mi++)
            af[mi] = *(const bf16x8*)&sA[(mi * 16 + lm) * 32 + sw];
        #pragma unroll
        for (int ni = 0; ni < 4; ni++)
            bfr[ni] = *(const bf16x8*)&sB[(ni * 16 + lm) * 32 + sw];
        // fragments fully landed in VGPRs before next iter's issue may
        // overwrite this phase ("memory" clobber pins the loads above).
        asm volatile("s_waitcnt lgkmcnt(0)" ::: "memory");

        #pragma unroll
        for (int mi = 0; mi < 4; mi++)
            #pragma unroll
            for (int ni = 0; ni < 4; ni++)
                acc[mi][ni] = __builtin_amdgcn_mfma_f32_16x16x32_bf16(
                    af[mi], bfr[ni], acc[mi][ni], 0, 0, 0);
    }

    // Epilogue — per-wave, no LDS, no sync. diag read straight from global
    // (L2-hot: 512 B per tile).
    const float temp = 7.62939453125e-07f;  // 1/(2*640*1024)
    unsigned short* dbase = dcov + (size_t)bt * D_DIM * D_DIM;
    float* rs = rowsum + (size_t)bt * D_DIM;
    const float* dg = diag + (size_t)bt * D_DIM;

    float dj[4];
    #pragma unroll
    for (int ni = 0; ni < 4; ni++) dj[ni] = dg[jt * 64 + ni * 16 + lm];

    float ts = 0.f;
    float cp[4] = {0.f, 0.f, 0.f, 0.f};

    #pragma unroll
    for (int mi = 0; mi < 4; mi++) {
        #pragma unroll
        for (int r = 0; r < 4; r++) {
            const int lrow = mi * 16 + quad * 4 + r;
            const int grow = it * 64 + lrow;
            const float di = dg[grow];
            float rp = 0.f;
            #pragma unroll
            for (int ni = 0; ni < 4; ni++) {
                const int gcol = jt * 64 + ni * 16 + lm;
                const float g = acc[mi][ni][r];
                const float v = sqrtf(fmaf(temp, fmaxf(di + dj[ni] - 2.f * g, 0.f), 1e-5f));
                dbase[(size_t)grow * D_DIM + gcol] = f2bf(v);
                rp += v;
                cp[ni] += v;
            }
            ts += rp;
            rp += __shfl_down(rp, 8, 16);
            rp += __shfl_down(rp, 4, 16);
            rp += __shfl_down(rp, 2, 16);
            rp += __shfl_down(rp, 1, 16);
            if (lm == 0) atomicAdd(&rs[grow], rp);
        }
    }
    if (!diagTile) {
        // mirrored lower tile (jt,it): its row sums == our column sums
        #pragma unroll
        for (int ni = 0; ni < 4; ni++) {
            float c = cp[ni];
            c += __shfl_down(c, 32);
            c += __shfl_down(c, 16);
            if (l < 16) atomicAdd(&rs[jt * 64 + ni * 16 + lm], c);
        }
    }
    #pragma unroll
    for (int off = 32; off > 0; off >>= 1) ts += __shfl_down(ts, off, 64);
    if (l == 0) atomicAdd(&tot[bt], diagTile ? ts : 2.f * ts);
}

// Kernel 3: double centering + triu gather (bf16 dcov read, fp32 out).
// Balanced: block q handles rows q and 639-q (lengths 640-q and q+1, sum 641).
__global__ void output_kernel(const unsigned short* __restrict__ dcov,
                              const float* __restrict__ rowsum,
                              const float* __restrict__ tot,
                              float* __restrict__ out) {
    const int b = blockIdx.x / 320;
    const int q = blockIdx.x - b * 320;
    const float inv_d = 1.f / (float)D_DIM;
    const float tm = tot[b] * (inv_d * inv_d);
    const float* rs = rowsum + (size_t)b * D_DIM;

    #pragma unroll
    for (int half = 0; half < 2; half++) {
        const int i = half ? (D_DIM - 1 - q) : q;
        const float rmi = rs[i] * inv_d;
        const unsigned short* drow = dcov + ((size_t)b * D_DIM + i) * D_DIM;
        float* orow = out + (size_t)b * OUT_ROW + (size_t)i * D_DIM - (size_t)i * (i - 1) / 2;
        for (int j = i + threadIdx.x; j < D_DIM; j += 256)
            orow[j - i] = bf2f(drow[j]) - rmi - rs[j] * inv_d + tm;
    }
}

extern "C" void kernel_launch(void* const* d_in, const int* in_sizes, int n_in,
                              void* d_out, int out_size, void* d_ws, size_t ws_size,
                              hipStream_t stream) {
    const float* x = (const float*)d_in[0];
    float* out = (float*)d_out;

    char* ws = (char*)d_ws;
    unsigned short* xb = (unsigned short*)ws;                 // 41,943,040 B
    size_t off = 41943040;
    float* diag = (float*)(ws + off);           off += 81920;
    unsigned short* dcov = (unsigned short*)(ws + off); off += 26214400;  // bf16
    float* rowsum = (float*)(ws + off);         off += 81920;
    float* tot = (float*)(ws + off);            off += 256;

    cast_diag_kernel<<<dim3(B_DIM * D_DIM), 256, 0, stream>>>(x, xb, diag, rowsum, tot);
    gemm_dcov_kernel<<<dim3(1760), 64, 0, stream>>>(xb, diag, dcov, rowsum, tot);
    output_kernel<<<dim3(B_DIM * 320), 256, 0, stream>>>(dcov, rowsum, tot, out);
}